// Round 8
// baseline (143.470 us; speedup 1.0000x reference)
//
#include <hip/hip_runtime.h>
#include <hip/hip_bf16.h>

#define T_DIM 8192
#define H_DIM 2048
#define D_DIM 1024
#define PAD_R 32          // zero lead rows of xb = scan warm-up window
#define KT2   32          // K steps of BK=32

typedef __bf16 bf16x8 __attribute__((ext_vector_type(8)));
typedef float floatx4 __attribute__((ext_vector_type(4)));
typedef unsigned short u16;

__device__ __forceinline__ u16 f2bf(float f) {
    __hip_bfloat16 b = __float2bfloat16(f);
    return *reinterpret_cast<u16*>(&b);
}
__device__ __forceinline__ float bf2f(u16 v) {
    return __uint_as_float((unsigned)v << 16);
}

#define GLDS(g, l) \
    __builtin_amdgcn_global_load_lds((const __attribute__((address_space(1))) void*)(g), \
                                     (__attribute__((address_space(3))) void*)(l), 16, 0, 0)

// ---------------------------------------------------------------------------
// fp32 -> bf16 convert: xb gets 32 leading ZERO rows (scan warm-up), then x;
// bb = B. ~63MB traffic -> ~10us at BW (measured at roofline).
// ---------------------------------------------------------------------------
__global__ __launch_bounds__(256) void conv_kernel(const float* __restrict__ x,
                                                   const float* __restrict__ Bm,
                                                   u16* __restrict__ xb,
                                                   u16* __restrict__ bb) {
    const int nPad4 = PAD_R * D_DIM / 4;
    const int nX4   = (T_DIM + PAD_R) * D_DIM / 4;
    const int nB4   = H_DIM * D_DIM / 4;
    int i = blockIdx.x * 256 + threadIdx.x;
    if (i < nX4) {
        ushort4 o;
        if (i < nPad4) {
            o.x = o.y = o.z = o.w = 0;
        } else {
            const float4 v = reinterpret_cast<const float4*>(x)[i - nPad4];
            o.x = f2bf(v.x); o.y = f2bf(v.y); o.z = f2bf(v.z); o.w = f2bf(v.w);
        }
        reinterpret_cast<ushort4*>(xb)[i] = o;
    } else {
        i -= nX4;
        if (i >= nB4) return;
        const float4 v = reinterpret_cast<const float4*>(Bm)[i];
        ushort4 o;
        o.x = f2bf(v.x); o.y = f2bf(v.y); o.z = f2bf(v.z); o.w = f2bf(v.w);
        reinterpret_cast<ushort4*>(bb)[i] = o;
    }
}

// ---------------------------------------------------------------------------
// Fused 160x128 GEMM + scan at THREE BLOCKS PER CU (r7 proved TLP is the
// lever: 1->2 blocks = -16%; unified VGPR+AGPR file caps us at 3 waves/SIMD
// for this wave-tile, so 3 blocks is the reachable occupancy step).
// 256 thr = 4 waves (2M x 2N), per-wave 80x64 (acc[5][4]), BK=32, 32 steps.
// LDS 45056B: A dbuf 2x[160][32] (20KB) + B TRI-buf 3x[128][32] (24KB);
// tri-buffer B makes the distance-2 restage race-free with 1 barrier/step:
// B(t+2) -> buf (t+2)%3, last read at t-1, drained at t-1's end barrier.
// A(t+1) -> opposite A-buf (last read t-1) distance-1.
// Per step t: 9 ds_reads (af5+bf4); GLDS A(t+1) x{2 + half(tid<128)};
// GLDS B(t+2) x2; lgkm(0)+sched_barrier; 20 MFMA; vmcnt(2) [outstanding
// B(t+1)x2 oldest + A(t+1)x{3|2} + B(t+2)x2 -> retire through A(t+1),
// uniform both wave classes]; barrier. Tail t>=KT2-2: vmcnt(0).
// BK=32 swizzle: granule g = kseg ^ ((row>>1)&3) -> every bank exactly 8
// accesses per wave b128 read (= conflict-free baseline); staging
// pre-swizzles the global column with the same involution.
// Epilogue (r0-proven): ut row-major [160][128] bf16 = 40960B (fits), col
// swizzle c ^= kseg*16 (2-way both sides = free); 2 half-scans per column
// (32 warm + 64 out), coalesced fp32 out. Warm-32: a^32 < 5e-5 = exact.
// ---------------------------------------------------------------------------
__device__ __forceinline__ bf16x8 lds_frag32(const u16* base, int row, int kseg) {
    const int g = (kseg ^ ((row >> 1) & 3)) * 8;
    return *reinterpret_cast<const bf16x8*>(base + row * 32 + g);
}

#define PH_BAR()    __builtin_amdgcn_s_barrier()
#define SCHEDB()    __builtin_amdgcn_sched_barrier(0)
#define LGKM0()     do { asm volatile("s_waitcnt lgkmcnt(0)" ::: "memory"); \
                         SCHEDB(); } while (0)

__global__ __launch_bounds__(256, 3) void gemm_kernel(const u16* __restrict__ xb,
                                                      const u16* __restrict__ bb,
                                                      const float* __restrict__ lam,
                                                      float* __restrict__ out) {
    __shared__ alignas(16) u16 smem[22528];   // 45056 B -> 3 blocks/CU
    u16* sA = smem;                    // 2 bufs x 5120 u16 ([160][32])
    u16* sB = smem + 10240;            // 3 bufs x 4096 u16 ([128][32])

    const int tid  = threadIdx.x;
    const int lane = tid & 63;
    const int wid  = tid >> 6;         // 0..3
    const int lrow = lane & 15;
    const int kseg = lane >> 4;
    const int wm   = (wid >> 1) * 80;
    const int wn   = (wid & 1) * 64;

    // T1: XCD-aware mapping (bijective; 1024 blocks = 8 xcd x 16 bn x 8 bm).
    const int bid = blockIdx.x;
    const int xcd = bid & 7, idx = bid >> 3;
    const int bn  = idx & 15;                  // 0..15
    const int bm  = xcd * 8 + (idx >> 4);      // 0..63

    // staging map: 64B rows, 4 thr/row; rS = tid>>2 (0..63 per 4KB unit);
    // global granule = (tid&3) ^ ((rS>>1)&3); unit offsets (64,128 rows)
    // preserve (row>>1)&3 -> swizzle matches reader.
    const int rS = tid >> 2;
    const int cS = (((tid & 3) ^ ((tid >> 3) & 3)) * 8);
    const u16* gA = xb + (size_t)(bm * 128 + rS) * D_DIM + cS;  // padded space
    const u16* gB = bb + (size_t)(bn * 128 + rS) * D_DIM + cS;

    floatx4 acc[5][4] = {};
    bf16x8 af[5], bf[4];

    // ---- prologue: A(0) x2.5, B(0) x2 -> buf0, B(1) x2 -> buf1.
    // vmcnt(2): retire A(0)+B(0), keep B(1) in flight (steady invariant).
    GLDS(gA, sA + tid * 8);
    GLDS(gA + (size_t)64 * D_DIM, sA + 2048 + tid * 8);
    if (tid < 128)
        GLDS(gA + (size_t)128 * D_DIM, sA + 4096 + tid * 8);
    GLDS(gB, sB + tid * 8);
    GLDS(gB + (size_t)64 * D_DIM, sB + 2048 + tid * 8);
    GLDS(gB + 32, sB + 4096 + tid * 8);
    GLDS(gB + (size_t)64 * D_DIM + 32, sB + 6144 + tid * 8);
    asm volatile("s_waitcnt vmcnt(2)" ::: "memory");
    PH_BAR();

    int bc = 0;                        // t % 3 (current B buf)
#pragma unroll 2
    for (int t = 0; t < KT2; ++t) {
        const u16* cA = sA + (t & 1) * 5120;
        const u16* cB = sB + bc * 4096;
        u16* wA       = sA + ((t + 1) & 1) * 5120;
        const int b2  = (bc == 0) ? 2 : bc - 1;       // (t+2) % 3
        u16* wB       = sB + b2 * 4096;

        // ---- ds_reads: af[0..4], bf[0..3]
#pragma unroll
        for (int mi = 0; mi < 5; ++mi)
            af[mi] = lds_frag32(cA, wm + mi * 16 + lrow, kseg);
#pragma unroll
        for (int nj = 0; nj < 4; ++nj)
            bf[nj] = lds_frag32(cB, wn + nj * 16 + lrow, kseg);
        SCHEDB();

        // ---- stage A(t+1) (opposite buf), B(t+2) (tri-buf, race-free)
        if (t + 1 < KT2) {
            const u16* ga1 = gA + (size_t)(t + 1) * 32;
            GLDS(ga1, wA + tid * 8);
            GLDS(ga1 + (size_t)64 * D_DIM, wA + 2048 + tid * 8);
            if (tid < 128)
                GLDS(ga1 + (size_t)128 * D_DIM, wA + 4096 + tid * 8);
        }
        if (t + 2 < KT2) {
            const u16* gb2 = gB + (size_t)(t + 2) * 32;
            GLDS(gb2, wB + tid * 8);
            GLDS(gb2 + (size_t)64 * D_DIM, wB + 2048 + tid * 8);
        }

        LGKM0();
        __builtin_amdgcn_s_setprio(1);
#pragma unroll
        for (int mi = 0; mi < 5; ++mi)
#pragma unroll
            for (int nj = 0; nj < 4; ++nj)
                acc[mi][nj] = __builtin_amdgcn_mfma_f32_16x16x32_bf16(
                    af[mi], bf[nj], acc[mi][nj], 0, 0, 0);
        __builtin_amdgcn_s_setprio(0);

        if (t < KT2 - 2) asm volatile("s_waitcnt vmcnt(2)" ::: "memory");
        else             asm volatile("s_waitcnt vmcnt(0)" ::: "memory");
        PH_BAR();

        bc = (bc == 2) ? 0 : bc + 1;
    }

    // ---- epilogue 1: acc -> ut row-major [160][128] bf16 (40960B),
    // col swizzle c ^= kseg*16 ((row>>2)&3 == kseg here) -> 2-way free.
    u16* ut = smem;
#pragma unroll
    for (int mi = 0; mi < 5; ++mi)
#pragma unroll
        for (int nj = 0; nj < 4; ++nj) {
            const int col = wn + nj * 16 + lrow;
#pragma unroll
            for (int r = 0; r < 4; ++r) {
                const int row = wm + mi * 16 + kseg * 4 + r;
                ut[row * 128 + (col ^ (kseg * 16))] = f2bf(acc[mi][nj][r]);
            }
        }
    __syncthreads();

    // ---- epilogue 2: two parallel half-scans per column (32 warm + 64 out).
    {
        const int half = tid >> 7;          // 0 or 1
        const int c    = tid & 127;
        const float a  = 1.0f / (1.0f + __expf(-lam[bn * 128 + c]));
        const int rb = half * 64;
        float h = 0.0f;
#pragma unroll 8
        for (int q = 0; q < 32; ++q) {
            const int l = rb + q;
            h = fmaf(a, h, bf2f(ut[l * 128 + (c ^ (((l >> 2) & 3) * 16))]));
        }
        float* op = out + (size_t)(bm * 128 + rb) * H_DIM + bn * 128 + c;
#pragma unroll 8
        for (int q = 0; q < 64; ++q) {
            const int l = rb + 32 + q;
            h = fmaf(a, h, bf2f(ut[l * 128 + (c ^ (((l >> 2) & 3) * 16))]));
            op[(size_t)q * H_DIM] = h;
        }
    }
}

// ---------------------------------------------------------------------------
extern "C" void kernel_launch(void* const* d_in, const int* in_sizes, int n_in,
                              void* d_out, int out_size, void* d_ws, size_t ws_size,
                              hipStream_t stream) {
    const float* x   = (const float*)d_in[0];   // [T, D]
    const float* lam = (const float*)d_in[1];   // [H]
    const float* B   = (const float*)d_in[2];   // [H, D]
    float* out = (float*)d_out;                 // [T, H]

    // ws: xb [T+32][D] bf16 (16.9MB) + bb [H][D] bf16 (4.2MB) = 21MB.
    u16* xb = (u16*)d_ws;
    u16* bb = xb + (size_t)(T_DIM + PAD_R) * D_DIM;

    const int n4 = ((T_DIM + PAD_R) * D_DIM + H_DIM * D_DIM) / 4;
    conv_kernel<<<(n4 + 255) / 256, 256, 0, stream>>>(x, B, xb, bb);
    gemm_kernel<<<(H_DIM / 128) * (T_DIM / 128), 256, 0, stream>>>(xb, bb, lam, out);
}

// Round 9
// 133.803 us; speedup vs baseline: 1.0722x; 1.0722x over previous
//
#include <hip/hip_runtime.h>
#include <hip/hip_bf16.h>

#define T_DIM 8192
#define H_DIM 2048
#define D_DIM 1024
#define PAD_R 32          // zero lead rows of xb = scan warm-up window
#define KT    16          // K tiles of BK=64
#define USTR  164         // u-tile col stride (u16), mult of 4 for b64 align

typedef __bf16 bf16x8 __attribute__((ext_vector_type(8)));
typedef float floatx4 __attribute__((ext_vector_type(4)));
typedef unsigned short u16;

__device__ __forceinline__ u16 f2bf(float f) {
    __hip_bfloat16 b = __float2bfloat16(f);
    return *reinterpret_cast<u16*>(&b);
}
__device__ __forceinline__ float bf2f(u16 v) {
    return __uint_as_float((unsigned)v << 16);
}

#define GLDS(g, l) \
    __builtin_amdgcn_global_load_lds((const __attribute__((address_space(1))) void*)(g), \
                                     (__attribute__((address_space(3))) void*)(l), 16, 0, 0)

// ---------------------------------------------------------------------------
// fp32 -> bf16 convert: xb gets 32 leading ZERO rows (scan warm-up), then x;
// bb = B. ~63MB traffic -> ~10us at BW (measured at roofline).
// ---------------------------------------------------------------------------
__global__ __launch_bounds__(256) void conv_kernel(const float* __restrict__ x,
                                                   const float* __restrict__ Bm,
                                                   u16* __restrict__ xb,
                                                   u16* __restrict__ bb) {
    const int nPad4 = PAD_R * D_DIM / 4;
    const int nX4   = (T_DIM + PAD_R) * D_DIM / 4;
    const int nB4   = H_DIM * D_DIM / 4;
    int i = blockIdx.x * 256 + threadIdx.x;
    if (i < nX4) {
        ushort4 o;
        if (i < nPad4) {
            o.x = o.y = o.z = o.w = 0;
        } else {
            const float4 v = reinterpret_cast<const float4*>(x)[i - nPad4];
            o.x = f2bf(v.x); o.y = f2bf(v.y); o.z = f2bf(v.z); o.w = f2bf(v.w);
        }
        reinterpret_cast<ushort4*>(xb)[i] = o;
    } else {
        i -= nX4;
        if (i >= nB4) return;
        const float4 v = reinterpret_cast<const float4*>(Bm)[i];
        ushort4 o;
        o.x = f2bf(v.x); o.y = f2bf(v.y); o.z = f2bf(v.z); o.w = f2bf(v.w);
        reinterpret_cast<ushort4*>(bb)[i] = o;
    }
}

// ---------------------------------------------------------------------------
// Fused 160x128 GEMM + scan: r7's proven 2-phase structure (read-heavy P1 /
// read-free P2 -- r8 showed full-drain-every-phase costs 20%), now at
// 8 WAVES x 2 BLOCKS per CU = 4 waves/SIMD (r7 was 2/SIMD; TLP is the lever).
// 512 thr = 8 waves (2M x 4N), per-wave 80x32 (acc[5][2]), BK=64, KT=16.
// LDS 73728B: A dbuf 2x[160][64] (40KB) + B dbuf 2x[128][64] (32KB) -> 2/CU.
// Per K-tile t:
//  P1: ds_read 14 frags, pinned order {af[.][0]x5, bf[.][0]x2} | {kx1 7};
//      GLDS A(t+1) x{2 + half(tid<256)} -> opposite A-buf; lgkmcnt(7) ->
//      10 MFMA kx0; lgkmcnt(0) [drains kx1 -> B-restage safe]; BAR.
//  P2: GLDS B(t+2) x2 -> same-parity B-buf (B(t) reads drained at P1);
//      10 MFMA kx1 (read-free); vmcnt(2) [outstanding B(t+1)2 + A(t+1){3|2}
//      + B(t+2)2 -> retire through A(t+1), uniform both classes]; BAR.
// Granule-XOR swizzle (col ^= (row&7)*8) both sides -> 0 bank conflicts.
// Epilogue: u-tile col-major [128][USTR] bf16 (b64 repack), 4 quarter-scans
// per column (32 warm + 32 out each), coalesced fp32 out.
// Warm-32 recompute: a^32 < 5e-5 -> exact at tolerance (proven r0-r8).
// ---------------------------------------------------------------------------
__device__ __forceinline__ bf16x8 lds_frag(const u16* base, int row, int kx, int kseg) {
    const int cp = (kx + kseg * 8) ^ ((row & 7) * 8);
    return *reinterpret_cast<const bf16x8*>(base + row * 64 + cp);
}

#define MFMA_K(KX)                                                                   \
    _Pragma("unroll")                                                                \
    for (int mi = 0; mi < 5; ++mi)                                                   \
        _Pragma("unroll")                                                            \
        for (int nj = 0; nj < 2; ++nj)                                               \
            acc[mi][nj] = __builtin_amdgcn_mfma_f32_16x16x32_bf16(                   \
                af[mi][KX], bf[nj][KX], acc[mi][nj], 0, 0, 0);

#define PH_BAR()    __builtin_amdgcn_s_barrier()
#define SCHEDB()    __builtin_amdgcn_sched_barrier(0)
#define LGKM(N)     do { asm volatile("s_waitcnt lgkmcnt(" #N ")" ::: "memory"); \
                         SCHEDB(); } while (0)

__global__ __launch_bounds__(512, 4) void gemm_kernel(const u16* __restrict__ xb,
                                                      const u16* __restrict__ bb,
                                                      const float* __restrict__ lam,
                                                      float* __restrict__ out) {
    __shared__ alignas(16) u16 smem[36864];   // 73728 B -> 2 blocks/CU
    u16* sA = smem;                    // 2 bufs x 10240 u16 ([160][64])
    u16* sB = smem + 20480;            // 2 bufs x  8192 u16 ([128][64])

    const int tid  = threadIdx.x;
    const int lane = tid & 63;
    const int wid  = tid >> 6;         // 0..7
    const int lrow = lane & 15;
    const int kseg = lane >> 4;
    const int wm   = (wid >> 2) * 80;  // 2 M-groups
    const int wn   = (wid & 3) * 32;   // 4 N-groups

    // T1: XCD-aware mapping (bijective; 1024 blocks = 8 xcd x 16 bn x 8 bm).
    const int bid = blockIdx.x;
    const int xcd = bid & 7, idx = bid >> 3;
    const int bn  = idx & 15;                  // 0..15
    const int bm  = xcd * 8 + (idx >> 4);      // 0..63

    // staging map: 512 thr * 16B = 64 rows per GLDS unit; unit offsets are
    // multiples of 64 rows -> r&7 preserved -> swizzle matches reader.
    const int rS = tid >> 3;                   // 0..63
    const int cS = ((tid & 7) * 8) ^ ((rS & 7) * 8);
    const u16* gA = xb + (size_t)(bm * 128 + rS) * D_DIM + cS;  // padded space
    const u16* gB = bb + (size_t)(bn * 128 + rS) * D_DIM + cS;

    floatx4 acc[5][2] = {};
    bf16x8 af[5][2], bf[2][2];

    // ---- prologue: A(0) x2.5, B(0) x2, B(1) x2. vmcnt(2): retire A(0)+B(0),
    // keep B(1) in flight (uniform: tid<256 7-2=5 retired, else 6-2=4).
    GLDS(gA, sA + tid * 8);
    GLDS(gA + (size_t)64 * D_DIM, sA + 4096 + tid * 8);
    if (tid < 256)
        GLDS(gA + (size_t)128 * D_DIM, sA + 8192 + tid * 8);
    GLDS(gB, sB + tid * 8);
    GLDS(gB + (size_t)64 * D_DIM, sB + 4096 + tid * 8);
    GLDS(gB + 64, sB + 8192 + tid * 8);
    GLDS(gB + (size_t)64 * D_DIM + 64, sB + 12288 + tid * 8);
    asm volatile("s_waitcnt vmcnt(2)" ::: "memory");
    PH_BAR();

#pragma unroll 2
    for (int t = 0; t < KT; ++t) {
        const u16* cA  = sA + (t & 1) * 10240;
        const u16* cB  = sB + (t & 1) * 8192;
        u16* dA        = sA + ((t + 1) & 1) * 10240;  // A(t+1): opposite buf
        u16* dB        = sB + (t & 1) * 8192;         // B(t+2): same parity
        const u16* ga1 = gA + (size_t)(t + 1) * 64;   // deref'd only if guarded
        const u16* gb2 = gB + (size_t)(t + 2) * 64;

        // ======== P1: reads {kx0: af5+bf2} | {kx1: af5+bf2}; stage A(t+1)
#pragma unroll
        for (int mi = 0; mi < 5; ++mi)
            af[mi][0] = lds_frag(cA, wm + mi * 16 + lrow, 0, kseg);
#pragma unroll
        for (int nj = 0; nj < 2; ++nj)
            bf[nj][0] = lds_frag(cB, wn + nj * 16 + lrow, 0, kseg);
        SCHEDB();   // pin: kx1 reads issue AFTER the 7 above (counted lgkm)
#pragma unroll
        for (int mi = 0; mi < 5; ++mi)
            af[mi][1] = lds_frag(cA, wm + mi * 16 + lrow, 32, kseg);
#pragma unroll
        for (int nj = 0; nj < 2; ++nj)
            bf[nj][1] = lds_frag(cB, wn + nj * 16 + lrow, 32, kseg);
        SCHEDB();
        if (t + 1 < KT) {
            GLDS(ga1, dA + tid * 8);
            GLDS(ga1 + (size_t)64 * D_DIM, dA + 4096 + tid * 8);
            if (tid < 256)
                GLDS(ga1 + (size_t)128 * D_DIM, dA + 8192 + tid * 8);
        }
        LGKM(7);                       // kx0 frags landed (DS in-order)
        __builtin_amdgcn_s_setprio(1);
        MFMA_K(0)
        __builtin_amdgcn_s_setprio(0);
        LGKM(0);                       // kx1 landed -> P2 B-restage is safe
        PH_BAR();

        // ======== P2: stage B(t+2); MFMA kx1 (read-free); counted vmcnt
        if (t + 2 < KT) {
            GLDS(gb2, dB + tid * 8);
            GLDS(gb2 + (size_t)64 * D_DIM, dB + 4096 + tid * 8);
        }
        __builtin_amdgcn_s_setprio(1);
        MFMA_K(1)
        __builtin_amdgcn_s_setprio(0);
        if (t < KT - 2) asm volatile("s_waitcnt vmcnt(2)" ::: "memory");
        else            asm volatile("s_waitcnt vmcnt(0)" ::: "memory");
        PH_BAR();
    }

    // ---- epilogue 1: acc -> LDS u-tile, COLUMN-major [128][USTR] bf16.
    // Lane's 4 acc values (rows r0..r0+3 of one col) -> one ds_write_b64.
    u16* ut = smem;
#pragma unroll
    for (int mi = 0; mi < 5; ++mi)
#pragma unroll
        for (int nj = 0; nj < 2; ++nj) {
            const int col  = wn + nj * 16 + lrow;
            const int row0 = wm + mi * 16 + kseg * 4;
            ushort4 w;
            w.x = f2bf(acc[mi][nj][0]); w.y = f2bf(acc[mi][nj][1]);
            w.z = f2bf(acc[mi][nj][2]); w.w = f2bf(acc[mi][nj][3]);
            *reinterpret_cast<ushort4*>(ut + col * USTR + row0) = w;
        }
    __syncthreads();

    // ---- epilogue 2: four quarter-scans per column (32 warm + 32 out each),
    // ds_read_b64 (4 rows per read), coalesced fp32 stores.
    {
        const int q = tid >> 7;             // 0..3
        const int c = tid & 127;
        const float a = 1.0f / (1.0f + __expf(-lam[bn * 128 + c]));
        const u16* colp = ut + c * USTR;
        const int rb = q * 32;
        float h = 0.0f;
#pragma unroll
        for (int qb = 0; qb < 8; ++qb) {
            const ushort4 v = *reinterpret_cast<const ushort4*>(colp + rb + qb * 4);
            h = fmaf(a, h, bf2f(v.x)); h = fmaf(a, h, bf2f(v.y));
            h = fmaf(a, h, bf2f(v.z)); h = fmaf(a, h, bf2f(v.w));
        }
        float* op = out + (size_t)(bm * 128 + rb) * H_DIM + bn * 128 + c;
#pragma unroll
        for (int qb = 0; qb < 8; ++qb) {
            const ushort4 v = *reinterpret_cast<const ushort4*>(colp + rb + 32 + qb * 4);
            h = fmaf(a, h, bf2f(v.x)); op[(size_t)(qb * 4 + 0) * H_DIM] = h;
            h = fmaf(a, h, bf2f(v.y)); op[(size_t)(qb * 4 + 1) * H_DIM] = h;
            h = fmaf(a, h, bf2f(v.z)); op[(size_t)(qb * 4 + 2) * H_DIM] = h;
            h = fmaf(a, h, bf2f(v.w)); op[(size_t)(qb * 4 + 3) * H_DIM] = h;
        }
    }
}

// ---------------------------------------------------------------------------
extern "C" void kernel_launch(void* const* d_in, const int* in_sizes, int n_in,
                              void* d_out, int out_size, void* d_ws, size_t ws_size,
                              hipStream_t stream) {
    const float* x   = (const float*)d_in[0];   // [T, D]
    const float* lam = (const float*)d_in[1];   // [H]
    const float* B   = (const float*)d_in[2];   // [H, D]
    float* out = (float*)d_out;                 // [T, H]

    // ws: xb [T+32][D] bf16 (16.9MB) + bb [H][D] bf16 (4.2MB) = 21MB.
    u16* xb = (u16*)d_ws;
    u16* bb = xb + (size_t)(T_DIM + PAD_R) * D_DIM;

    const int n4 = ((T_DIM + PAD_R) * D_DIM + H_DIM * D_DIM) / 4;
    conv_kernel<<<(n4 + 255) / 256, 256, 0, stream>>>(x, B, xb, bb);
    gemm_kernel<<<(H_DIM / 128) * (T_DIM / 128), 512, 0, stream>>>(xb, bb, lam, out);
}